// Round 1
// baseline (1440.984 us; speedup 1.0000x reference)
//
#include <hip/hip_runtime.h>

#define N1V 100000
#define N2V 500
#define NEV 1000000
#define ALPHAV 0.2f

__device__ __forceinline__ float wave_sum(float v) {
#pragma unroll
  for (int off = 32; off > 0; off >>= 1) v += __shfl_xor(v, off, 64);
  return v;
}

// ---------------- prep: c[320] = a^T @ a_2 ; aT[p*128+j] = a[j*320+p] ----------------
__global__ __launch_bounds__(256) void k_prep(const float* __restrict__ a,
                                              const float* __restrict__ a2,
                                              float* __restrict__ c,
                                              float* __restrict__ aT) {
  int b = blockIdx.x;
  if (b < 160) {
    int id = b * 256 + threadIdx.x;          // 0..40959
    int p = id >> 7, j = id & 127;
    aT[id] = a[j * 320 + p];
  } else {
    int p = (b - 160) * 256 + threadIdx.x;   // 0..511
    if (p < 320) {
      float s = 0.f;
      for (int k = 0; k < 128; ++k) s += a2[k] * a[k * 320 + p];
      c[p] = s;
    }
  }
}

// ---------------- z2[t] = x2[t] . c2 ----------------
__global__ __launch_bounds__(256) void k_z2(const float* __restrict__ x2,
                                            const float* __restrict__ c,
                                            float* __restrict__ z2g) {
  int w = (blockIdx.x * 256 + threadIdx.x) >> 6;
  int l = threadIdx.x & 63;
  if (w >= N2V) return;
  float p = x2[w * 128 + l] * c[128 + l] + x2[w * 128 + 64 + l] * c[192 + l];
  float s = wave_sum(p);
  if (l == 0) z2g[w] = s;
}

// ---------------- histogram ----------------
__global__ __launch_bounds__(256) void k_hist(const int* __restrict__ src,
                                              const int* __restrict__ dst,
                                              int* __restrict__ c1, int* __restrict__ c2) {
  for (int e = blockIdx.x * blockDim.x + threadIdx.x; e < NEV; e += gridDim.x * blockDim.x) {
    atomicAdd(&c1[src[e]], 1);
    atomicAdd(&c2[dst[e]], 1);
  }
}

// ---------------- scan (3-phase for N1; single block handles dst + partials) ----------------
__global__ __launch_bounds__(256) void k_scanA(const int* __restrict__ cnt,
                                               int* __restrict__ outp,
                                               int* __restrict__ partials, int n) {
  __shared__ int s[256];
  int tid = threadIdx.x;
  int base = blockIdx.x * 2048 + tid * 8;
  int v[8]; int tot = 0;
#pragma unroll
  for (int j = 0; j < 8; ++j) { int idx = base + j; v[j] = (idx < n) ? cnt[idx] : 0; tot += v[j]; }
  s[tid] = tot; __syncthreads();
  for (int off = 1; off < 256; off <<= 1) {
    int tv = 0;
    if (tid >= off) tv = s[tid - off];
    __syncthreads();
    if (tid >= off) s[tid] += tv;
    __syncthreads();
  }
  int run = s[tid] - tot;
#pragma unroll
  for (int j = 0; j < 8; ++j) { int idx = base + j; if (idx < n) outp[idx] = run; run += v[j]; }
  if (tid == 255) partials[blockIdx.x] = s[255];
}

__global__ __launch_bounds__(512) void k_scanB(int* __restrict__ partials, int nPart,
                                               int* __restrict__ cnt2, int* __restrict__ rp2,
                                               int* __restrict__ cur2) {
  __shared__ int s[512];
  int tid = threadIdx.x;
  int v = (tid < N2V) ? cnt2[tid] : 0;
  s[tid] = v; __syncthreads();
  for (int off = 1; off < 512; off <<= 1) {
    int tv = 0;
    if (tid >= off) tv = s[tid - off];
    __syncthreads();
    if (tid >= off) s[tid] += tv;
    __syncthreads();
  }
  if (tid < N2V) { int ex = s[tid] - v; rp2[tid] = ex; cur2[tid] = ex; }
  if (tid == N2V - 1) rp2[N2V] = s[tid];
  if (tid == 0) {
    int run = 0;
    for (int b = 0; b < nPart; ++b) { int t = partials[b]; partials[b] = run; run += t; }
  }
}

__global__ __launch_bounds__(256) void k_scanC(int* __restrict__ rp, int* __restrict__ cur,
                                               const int* __restrict__ partials, int n, int total) {
  int i = blockIdx.x * 256 + threadIdx.x;
  if (i < n) {
    int v = rp[i] + partials[i >> 11];
    rp[i] = v; cur[i] = v;
  }
  if (i == 0) rp[n] = total;
}

// ---------------- scatter into CSR ----------------
__global__ __launch_bounds__(256) void k_scatter(const int* __restrict__ src,
                                                 const int* __restrict__ dst,
                                                 int* __restrict__ cur1, int* __restrict__ cur2,
                                                 int* __restrict__ e1, int* __restrict__ e2) {
  for (int e = blockIdx.x * blockDim.x + threadIdx.x; e < NEV; e += gridDim.x * blockDim.x) {
    int p = atomicAdd(&cur1[src[e]], 1); e1[p] = e;
    int q = atomicAdd(&cur2[dst[e]], 1); e2[q] = e;
  }
}

// ---------------- main edge pass, grouped by src (one wave per entity) ----------------
__global__ __launch_bounds__(256) void k_src(const float* __restrict__ x1,
                                             const float* __restrict__ x2,
                                             const float* __restrict__ ee,
                                             const int* __restrict__ edge_dst,
                                             const float* __restrict__ c,
                                             const float* __restrict__ z2g,
                                             const int* __restrict__ rp1,
                                             const int* __restrict__ eidx,
                                             float* __restrict__ wbuf,
                                             float* __restrict__ sbuf1,
                                             float* __restrict__ rs1) {
  int wid = (blockIdx.x * 256 + threadIdx.x) >> 6;
  int l = threadIdx.x & 63;
  if (wid >= N1V) return;
  float c3l = c[256 + l];
  float xa = x1[wid * 128 + l], xb = x1[wid * 128 + 64 + l];
  float z1 = wave_sum(xa * c[l] + xb * c[64 + l]);
  int start = rp1[wid], end = rp1[wid + 1];
  float s2a = 0.f, s2b = 0.f, s1 = 0.f, rsum = 0.f;
  for (int p = start; p < end; ++p) {
    int e = eidx[p];
    float ev = ee[e * 64 + l];
    int d = edge_dst[e];
    float z3 = wave_sum(ev * c3l);
    float z = z1 + z2g[d] + z3;
    float zp = z > 0.f ? z : ALPHAV * z;
    float w = __expf(-zp);
    if (l == 0) wbuf[e] = w;
    rsum += w;
    s1 += w * ev;
    s2a += w * x2[d * 128 + l];
    s2b += w * x2[d * 128 + 64 + l];
  }
  float scale = (end > start) ? 1.0f / rsum : 0.f;
  sbuf1[wid * 192 + l] = s2a * scale;
  sbuf1[wid * 192 + 64 + l] = s2b * scale;
  sbuf1[wid * 192 + 128 + l] = s1 * scale;
  if (l == 0) rs1[wid] = (end > start) ? rsum : 0.f;
}

// ---------------- edge pass grouped by dst: partial accumulate (500 types x 8 chunks) ----------------
__global__ __launch_bounds__(256) void k_dst_partial(const float* __restrict__ x1,
                                                     const float* __restrict__ ee,
                                                     const int* __restrict__ edge_src,
                                                     const int* __restrict__ rp2,
                                                     const int* __restrict__ eidx2,
                                                     const float* __restrict__ wbuf,
                                                     float* __restrict__ acc2) {
  __shared__ float red[4][200];
  int t = blockIdx.x >> 3;
  int chunk = blockIdx.x & 7;
  int tid = threadIdx.x, wv = tid >> 6, l = tid & 63;
  int start = rp2[t], end = rp2[t + 1];
  float sxa = 0.f, sxb = 0.f, s3 = 0.f, rsum = 0.f;
  for (int p = start + chunk * 4 + wv; p < end; p += 32) {
    int e = eidx2[p];
    float w = wbuf[e];
    int s = edge_src[e];
    sxa += w * x1[s * 128 + l];
    sxb += w * x1[s * 128 + 64 + l];
    s3 += w * ee[e * 64 + l];
    rsum += w;
  }
  red[wv][l] = sxa; red[wv][64 + l] = sxb; red[wv][128 + l] = s3;
  if (l == 0) red[wv][192] = rsum;
  __syncthreads();
  if (tid < 193) {
    float v = red[0][tid] + red[1][tid] + red[2][tid] + red[3][tid];
    if (v != 0.f) atomicAdd(&acc2[t * 196 + tid], v);
  }
}

__global__ __launch_bounds__(256) void k_dst_final(const float* __restrict__ acc2,
                                                   float* __restrict__ sbuf2,
                                                   float* __restrict__ rs2) {
  int t = blockIdx.x, tid = threadIdx.x;
  float rtot = acc2[t * 196 + 192];
  float scale = rtot > 0.f ? 1.0f / rtot : 0.f;
  if (tid < 192) sbuf2[t * 192 + tid] = acc2[t * 196 + tid] * scale;
  if (tid == 192) rs2[t] = rtot;
}

// ---------------- fused output GEMM: out = mask * elu(A[M,320] @ a^T) ----------------
// mode 0 (entity): cols [0,128)=X row, [128,320)=S row (192 wide)
// mode 1 (type):   cols [0,128)=S[0..128), [128,256)=X row, [256,320)=S[128..192)
__global__ __launch_bounds__(256) void k_gemm(const float* __restrict__ X,
                                              const float* __restrict__ S,
                                              const float* __restrict__ aT,
                                              const float* __restrict__ rs,
                                              float* __restrict__ out,
                                              int M, int mode) {
  __shared__ float As[128][33];
  __shared__ float Bs[32][128];
  int tid = threadIdx.x;
  int row0 = blockIdx.x * 128;
  int tm = (tid >> 4) << 3;
  int tn = (tid & 15) << 3;
  float acc[8][8];
#pragma unroll
  for (int r = 0; r < 8; ++r)
#pragma unroll
    for (int cc = 0; cc < 8; ++cc) acc[r][cc] = 0.f;

  for (int k0 = 0; k0 < 320; k0 += 32) {
    // stage B: contiguous 4096 floats of aT
    const float4* bsrc = (const float4*)(aT + k0 * 128);
    float4* bdst = (float4*)(&Bs[0][0]);
#pragma unroll
    for (int q = 0; q < 4; ++q) bdst[tid + 256 * q] = bsrc[tid + 256 * q];
    // stage A
#pragma unroll
    for (int q = 0; q < 4; ++q) {
      int t0 = tid + 256 * q;
      int m = t0 >> 3;
      int kq = (t0 & 7) << 2;
      int gi = row0 + m;
      int p = k0 + kq;
      float4 v = make_float4(0.f, 0.f, 0.f, 0.f);
      if (gi < M) {
        const float* sp;
        if (mode == 0) sp = (p < 128) ? (X + gi * 128 + p) : (S + gi * 192 + (p - 128));
        else sp = (p >= 128 && p < 256) ? (X + gi * 128 + (p - 128))
                                        : (S + gi * 192 + (p < 128 ? p : p - 128));
        v = *(const float4*)sp;
      }
      As[m][kq + 0] = v.x; As[m][kq + 1] = v.y; As[m][kq + 2] = v.z; As[m][kq + 3] = v.w;
    }
    __syncthreads();
#pragma unroll
    for (int kk = 0; kk < 32; ++kk) {
      float af[8];
#pragma unroll
      for (int r = 0; r < 8; ++r) af[r] = As[tm + r][kk];
      float4 b0 = *(const float4*)&Bs[kk][tn];
      float4 b1 = *(const float4*)&Bs[kk][tn + 4];
      float bf[8] = {b0.x, b0.y, b0.z, b0.w, b1.x, b1.y, b1.z, b1.w};
#pragma unroll
      for (int r = 0; r < 8; ++r)
#pragma unroll
        for (int cc = 0; cc < 8; ++cc) acc[r][cc] += af[r] * bf[cc];
    }
    __syncthreads();
  }
#pragma unroll
  for (int r = 0; r < 8; ++r) {
    int gi = row0 + tm + r;
    if (gi < M) {
      float rsv = rs[gi];
      bool ok = rsv > 0.f;
      float4 o0, o1;
      float h;
      h = acc[r][0]; o0.x = ok ? (h > 0.f ? h : expm1f(h)) : 0.f;
      h = acc[r][1]; o0.y = ok ? (h > 0.f ? h : expm1f(h)) : 0.f;
      h = acc[r][2]; o0.z = ok ? (h > 0.f ? h : expm1f(h)) : 0.f;
      h = acc[r][3]; o0.w = ok ? (h > 0.f ? h : expm1f(h)) : 0.f;
      h = acc[r][4]; o1.x = ok ? (h > 0.f ? h : expm1f(h)) : 0.f;
      h = acc[r][5]; o1.y = ok ? (h > 0.f ? h : expm1f(h)) : 0.f;
      h = acc[r][6]; o1.z = ok ? (h > 0.f ? h : expm1f(h)) : 0.f;
      h = acc[r][7]; o1.w = ok ? (h > 0.f ? h : expm1f(h)) : 0.f;
      *(float4*)(out + gi * 128 + tn) = o0;
      *(float4*)(out + gi * 128 + tn + 4) = o1;
    }
  }
}

// =====================================================================================

static inline size_t align_up(size_t x, size_t a) { return (x + a - 1) & ~(a - 1); }

extern "C" void kernel_launch(void* const* d_in, const int* in_sizes, int n_in,
                              void* d_out, int out_size, void* d_ws, size_t ws_size,
                              hipStream_t stream) {
  const float* x1 = (const float*)d_in[0];
  const float* x2 = (const float*)d_in[1];
  const float* ee = (const float*)d_in[2];
  const float* a = (const float*)d_in[3];
  const float* a2 = (const float*)d_in[4];
  const int* esrc = (const int*)d_in[5];
  const int* edst = (const int*)d_in[6];
  float* out = (float*)d_out;

  char* base = (char*)d_ws;
  size_t off = 0;
  auto alloc = [&](size_t bytes) -> char* {
    char* p = base + off;
    off = align_up(off + bytes, 256);
    return p;
  };
  float* c = (float*)alloc(320 * 4);
  float* z2g = (float*)alloc(512 * 4);
  float* aT = (float*)alloc(320 * 128 * 4);
  int* rp1 = (int*)alloc((N1V + 1) * 4);
  int* cur1 = (int*)alloc(N1V * 4);
  int* rp2 = (int*)alloc(512 * 4);
  int* cur2 = (int*)alloc(512 * 4);
  int* partials = (int*)alloc(64 * 4);
  int* eidx1 = (int*)alloc(NEV * 4);
  int* eidx2 = (int*)alloc(NEV * 4);
  float* wbuf = (float*)alloc(NEV * 4);
  float* rs1 = (float*)alloc(N1V * 4);
  float* rs2 = (float*)alloc(512 * 4);
  float* sbuf1 = (float*)alloc((size_t)N1V * 192 * 4);
  float* sbuf2 = (float*)alloc(512 * 192 * 4);
  float* acc2 = (float*)alloc(512 * 196 * 4);
  (void)ws_size; (void)out_size; (void)n_in; (void)in_sizes;

  hipMemsetAsync(cur1, 0, N1V * 4, stream);
  hipMemsetAsync(cur2, 0, 512 * 4, stream);
  hipMemsetAsync(acc2, 0, 512 * 196 * 4, stream);

  hipLaunchKernelGGL(k_prep, dim3(162), dim3(256), 0, stream, a, a2, c, aT);
  hipLaunchKernelGGL(k_z2, dim3(125), dim3(256), 0, stream, x2, c, z2g);
  hipLaunchKernelGGL(k_hist, dim3(2048), dim3(256), 0, stream, esrc, edst, cur1, cur2);

  const int nScanBlocks = (N1V + 2047) / 2048;  // 49
  hipLaunchKernelGGL(k_scanA, dim3(nScanBlocks), dim3(256), 0, stream, cur1, rp1, partials, N1V);
  hipLaunchKernelGGL(k_scanB, dim3(1), dim3(512), 0, stream, partials, nScanBlocks, cur2, rp2, cur2);
  hipLaunchKernelGGL(k_scanC, dim3((N1V + 255) / 256), dim3(256), 0, stream, rp1, cur1, partials, N1V, NEV);
  hipLaunchKernelGGL(k_scatter, dim3(2048), dim3(256), 0, stream, esrc, edst, cur1, cur2, eidx1, eidx2);

  hipLaunchKernelGGL(k_src, dim3(N1V / 4), dim3(256), 0, stream,
                     x1, x2, ee, edst, c, z2g, rp1, eidx1, wbuf, sbuf1, rs1);
  hipLaunchKernelGGL(k_dst_partial, dim3(N2V * 8), dim3(256), 0, stream,
                     x1, ee, esrc, rp2, eidx2, wbuf, acc2);
  hipLaunchKernelGGL(k_dst_final, dim3(N2V), dim3(256), 0, stream, acc2, sbuf2, rs2);

  hipLaunchKernelGGL(k_gemm, dim3((N1V + 127) / 128), dim3(256), 0, stream,
                     x1, sbuf1, aT, rs1, out, N1V, 0);
  hipLaunchKernelGGL(k_gemm, dim3((N2V + 127) / 128), dim3(256), 0, stream,
                     x2, sbuf2, aT, rs2, out + (size_t)N1V * 128, N2V, 1);
}

// Round 2
// 897.517 us; speedup vs baseline: 1.6055x; 1.6055x over previous
//
#include <hip/hip_runtime.h>

#define N1V 100000
#define N2V 500
#define NEV 1000000
#define ALPHAV 0.2f
#define NB 256        // histogram/scatter blocks
#define CHUNK 3907    // ceil(NEV/NB)

__device__ __forceinline__ float wave_sum(float v) {
#pragma unroll
  for (int off = 32; off > 0; off >>= 1) v += __shfl_xor(v, off, 64);
  return v;
}

// ---------------- prep: c[320] = a^T @ a_2 ; aT[p*128+j] = a[j*320+p] ----------------
__global__ __launch_bounds__(256) void k_prep(const float* __restrict__ a,
                                              const float* __restrict__ a2,
                                              float* __restrict__ c,
                                              float* __restrict__ aT) {
  int b = blockIdx.x;
  if (b < 160) {
    int id = b * 256 + threadIdx.x;          // 0..40959
    int p = id >> 7, j = id & 127;
    aT[id] = a[j * 320 + p];
  } else {
    int p = (b - 160) * 256 + threadIdx.x;   // 0..511
    if (p < 320) {
      float s = 0.f;
      for (int k = 0; k < 128; ++k) s += a2[k] * a[k * 320 + p];
      c[p] = s;
    }
  }
}

// ---------------- z2[t] = x2[t] . c2 ----------------
__global__ __launch_bounds__(256) void k_z2(const float* __restrict__ x2,
                                            const float* __restrict__ c,
                                            float* __restrict__ z2g) {
  int w = (blockIdx.x * 256 + threadIdx.x) >> 6;
  int l = threadIdx.x & 63;
  if (w >= N2V) return;
  float p = x2[w * 128 + l] * c[128 + l] + x2[w * 128 + 64 + l] * c[192 + l];
  float s = wave_sum(p);
  if (l == 0) z2g[w] = s;
}

// ---------------- histogram: global atomics for src (100K buckets), LDS for dst ----------------
__global__ __launch_bounds__(256) void k_hist(const int* __restrict__ src,
                                              const int* __restrict__ dst,
                                              int* __restrict__ c1,
                                              int* __restrict__ hblk) {
  __shared__ int h[512];
  for (int i = threadIdx.x; i < 512; i += 256) h[i] = 0;
  __syncthreads();
  int b = blockIdx.x;
  int b0 = b * CHUNK, b1 = min(b0 + CHUNK, NEV);
  for (int e = b0 + threadIdx.x; e < b1; e += 256) {
    atomicAdd(&c1[src[e]], 1);
    atomicAdd(&h[dst[e]], 1);
  }
  __syncthreads();
  for (int i = threadIdx.x; i < 512; i += 256) hblk[b * 512 + i] = h[i];
}

// ---------------- column scan: hblk[b][t] -> exclusive prefix over b; tot2[t] ----------------
__global__ __launch_bounds__(256) void k_colscan(int* __restrict__ hblk,
                                                 int* __restrict__ tot2) {
  __shared__ int s[256];
  int t = blockIdx.x;            // 0..511
  int b = threadIdx.x;           // 0..255
  int v = hblk[b * 512 + t];
  s[b] = v; __syncthreads();
  for (int off = 1; off < 256; off <<= 1) {
    int tv = (b >= off) ? s[b - off] : 0;
    __syncthreads();
    if (b >= off) s[b] += tv;
    __syncthreads();
  }
  hblk[b * 512 + t] = s[b] - v;      // exclusive over blocks
  if (b == 255) tot2[t] = s[255];
}

// ---------------- scan for src counts (3-phase) + dst totals (single block) ----------------
__global__ __launch_bounds__(256) void k_scanA(const int* __restrict__ cnt,
                                               int* __restrict__ outp,
                                               int* __restrict__ partials, int n) {
  __shared__ int s[256];
  int tid = threadIdx.x;
  int base = blockIdx.x * 2048 + tid * 8;
  int v[8]; int tot = 0;
#pragma unroll
  for (int j = 0; j < 8; ++j) { int idx = base + j; v[j] = (idx < n) ? cnt[idx] : 0; tot += v[j]; }
  s[tid] = tot; __syncthreads();
  for (int off = 1; off < 256; off <<= 1) {
    int tv = 0;
    if (tid >= off) tv = s[tid - off];
    __syncthreads();
    if (tid >= off) s[tid] += tv;
    __syncthreads();
  }
  int run = s[tid] - tot;
#pragma unroll
  for (int j = 0; j < 8; ++j) { int idx = base + j; if (idx < n) outp[idx] = run; run += v[j]; }
  if (tid == 255) partials[blockIdx.x] = s[255];
}

__global__ __launch_bounds__(512) void k_scanB(int* __restrict__ partials, int nPart,
                                               const int* __restrict__ tot2,
                                               int* __restrict__ rp2) {
  __shared__ int s[512];
  int tid = threadIdx.x;
  int v = (tid < N2V) ? tot2[tid] : 0;
  s[tid] = v; __syncthreads();
  for (int off = 1; off < 512; off <<= 1) {
    int tv = 0;
    if (tid >= off) tv = s[tid - off];
    __syncthreads();
    if (tid >= off) s[tid] += tv;
    __syncthreads();
  }
  if (tid < N2V) rp2[tid] = s[tid] - v;
  if (tid == N2V - 1) rp2[N2V] = s[tid];
  if (tid == 0) {
    int run = 0;
    for (int b = 0; b < nPart; ++b) { int t = partials[b]; partials[b] = run; run += t; }
  }
}

__global__ __launch_bounds__(256) void k_scanC(int* __restrict__ rp, int* __restrict__ cur,
                                               const int* __restrict__ partials, int n, int total) {
  int i = blockIdx.x * 256 + threadIdx.x;
  if (i < n) {
    int v = rp[i] + partials[i >> 11];
    rp[i] = v; cur[i] = v;
  }
  if (i == 0) rp[n] = total;
}

// ---------------- scatter into CSR: dst side atomic-free via precomputed block bases ----------------
__global__ __launch_bounds__(256) void k_scatter(const int* __restrict__ src,
                                                 const int* __restrict__ dst,
                                                 int* __restrict__ cur1,
                                                 const int* __restrict__ hblk,
                                                 const int* __restrict__ rp2,
                                                 int* __restrict__ e1, int* __restrict__ e2) {
  __shared__ int h[512];
  __shared__ int basep[512];
  int b = blockIdx.x;
  int b0 = b * CHUNK, b1 = min(b0 + CHUNK, NEV);
  for (int i = threadIdx.x; i < 512; i += 256) {
    basep[i] = ((i < N2V) ? rp2[i] : 0) + hblk[b * 512 + i];
    h[i] = 0;
  }
  __syncthreads();
  for (int e = b0 + threadIdx.x; e < b1; e += 256) {
    int sv = src[e], d = dst[e];
    int p = atomicAdd(&cur1[sv], 1);
    e1[p] = e;
    int loc = atomicAdd(&h[d], 1);
    e2[basep[d] + loc] = e;
  }
}

// ---------------- main edge pass, grouped by src (one wave per entity) ----------------
__global__ __launch_bounds__(256) void k_src(const float* __restrict__ x1,
                                             const float* __restrict__ x2,
                                             const float* __restrict__ ee,
                                             const int* __restrict__ edge_dst,
                                             const float* __restrict__ c,
                                             const float* __restrict__ z2g,
                                             const int* __restrict__ rp1,
                                             const int* __restrict__ eidx,
                                             float* __restrict__ wbuf,
                                             float* __restrict__ sbuf1,
                                             float* __restrict__ rs1) {
  int wid = (blockIdx.x * 256 + threadIdx.x) >> 6;
  int l = threadIdx.x & 63;
  if (wid >= N1V) return;
  float c3l = c[256 + l];
  float xa = x1[wid * 128 + l], xb = x1[wid * 128 + 64 + l];
  float z1 = wave_sum(xa * c[l] + xb * c[64 + l]);
  int start = rp1[wid], end = rp1[wid + 1];
  float s2a = 0.f, s2b = 0.f, s1 = 0.f, rsum = 0.f;
  for (int p = start; p < end; ++p) {
    int e = eidx[p];
    float ev = ee[e * 64 + l];
    int d = edge_dst[e];
    float z3 = wave_sum(ev * c3l);
    float z = z1 + z2g[d] + z3;
    float zp = z > 0.f ? z : ALPHAV * z;
    float w = __expf(-zp);
    if (l == 0) wbuf[e] = w;
    rsum += w;
    s1 += w * ev;
    s2a += w * x2[d * 128 + l];
    s2b += w * x2[d * 128 + 64 + l];
  }
  float scale = (end > start) ? 1.0f / rsum : 0.f;
  sbuf1[wid * 192 + l] = s2a * scale;
  sbuf1[wid * 192 + 64 + l] = s2b * scale;
  sbuf1[wid * 192 + 128 + l] = s1 * scale;
  if (l == 0) rs1[wid] = (end > start) ? rsum : 0.f;
}

// ---------------- edge pass grouped by dst: partial accumulate (500 types x 8 chunks) ----------------
__global__ __launch_bounds__(256) void k_dst_partial(const float* __restrict__ x1,
                                                     const float* __restrict__ ee,
                                                     const int* __restrict__ edge_src,
                                                     const int* __restrict__ rp2,
                                                     const int* __restrict__ eidx2,
                                                     const float* __restrict__ wbuf,
                                                     float* __restrict__ acc2) {
  __shared__ float red[4][200];
  int t = blockIdx.x >> 3;
  int chunk = blockIdx.x & 7;
  int tid = threadIdx.x, wv = tid >> 6, l = tid & 63;
  int start = rp2[t], end = rp2[t + 1];
  float sxa = 0.f, sxb = 0.f, s3 = 0.f, rsum = 0.f;
  for (int p = start + chunk * 4 + wv; p < end; p += 32) {
    int e = eidx2[p];
    float w = wbuf[e];
    int s = edge_src[e];
    sxa += w * x1[s * 128 + l];
    sxb += w * x1[s * 128 + 64 + l];
    s3 += w * ee[e * 64 + l];
    rsum += w;
  }
  red[wv][l] = sxa; red[wv][64 + l] = sxb; red[wv][128 + l] = s3;
  if (l == 0) red[wv][192] = rsum;
  __syncthreads();
  if (tid < 193) {
    float v = red[0][tid] + red[1][tid] + red[2][tid] + red[3][tid];
    if (v != 0.f) atomicAdd(&acc2[t * 196 + tid], v);
  }
}

__global__ __launch_bounds__(256) void k_dst_final(const float* __restrict__ acc2,
                                                   float* __restrict__ sbuf2,
                                                   float* __restrict__ rs2) {
  int t = blockIdx.x, tid = threadIdx.x;
  float rtot = acc2[t * 196 + 192];
  float scale = rtot > 0.f ? 1.0f / rtot : 0.f;
  if (tid < 192) sbuf2[t * 192 + tid] = acc2[t * 196 + tid] * scale;
  if (tid == 192) rs2[t] = rtot;
}

// ---------------- fused output GEMM: out = mask * elu(A[M,320] @ a^T) ----------------
// mode 0 (entity): cols [0,128)=X row, [128,320)=S row (192 wide)
// mode 1 (type):   cols [0,128)=S[0..128), [128,256)=X row, [256,320)=S[128..192)
__global__ __launch_bounds__(256) void k_gemm(const float* __restrict__ X,
                                              const float* __restrict__ S,
                                              const float* __restrict__ aT,
                                              const float* __restrict__ rs,
                                              float* __restrict__ out,
                                              int M, int mode) {
  __shared__ float As[128][33];
  __shared__ float Bs[32][128];
  int tid = threadIdx.x;
  int row0 = blockIdx.x * 128;
  int tm = (tid >> 4) << 3;
  int tn = (tid & 15) << 3;
  float acc[8][8];
#pragma unroll
  for (int r = 0; r < 8; ++r)
#pragma unroll
    for (int cc = 0; cc < 8; ++cc) acc[r][cc] = 0.f;

  for (int k0 = 0; k0 < 320; k0 += 32) {
    const float4* bsrc = (const float4*)(aT + k0 * 128);
    float4* bdst = (float4*)(&Bs[0][0]);
#pragma unroll
    for (int q = 0; q < 4; ++q) bdst[tid + 256 * q] = bsrc[tid + 256 * q];
#pragma unroll
    for (int q = 0; q < 4; ++q) {
      int t0 = tid + 256 * q;
      int m = t0 >> 3;
      int kq = (t0 & 7) << 2;
      int gi = row0 + m;
      int p = k0 + kq;
      float4 v = make_float4(0.f, 0.f, 0.f, 0.f);
      if (gi < M) {
        const float* sp;
        if (mode == 0) sp = (p < 128) ? (X + gi * 128 + p) : (S + gi * 192 + (p - 128));
        else sp = (p >= 128 && p < 256) ? (X + gi * 128 + (p - 128))
                                        : (S + gi * 192 + (p < 128 ? p : p - 128));
        v = *(const float4*)sp;
      }
      As[m][kq + 0] = v.x; As[m][kq + 1] = v.y; As[m][kq + 2] = v.z; As[m][kq + 3] = v.w;
    }
    __syncthreads();
#pragma unroll
    for (int kk = 0; kk < 32; ++kk) {
      float af[8];
#pragma unroll
      for (int r = 0; r < 8; ++r) af[r] = As[tm + r][kk];
      float4 b0 = *(const float4*)&Bs[kk][tn];
      float4 b1 = *(const float4*)&Bs[kk][tn + 4];
      float bf[8] = {b0.x, b0.y, b0.z, b0.w, b1.x, b1.y, b1.z, b1.w};
#pragma unroll
      for (int r = 0; r < 8; ++r)
#pragma unroll
        for (int cc = 0; cc < 8; ++cc) acc[r][cc] += af[r] * bf[cc];
    }
    __syncthreads();
  }
#pragma unroll
  for (int r = 0; r < 8; ++r) {
    int gi = row0 + tm + r;
    if (gi < M) {
      float rsv = rs[gi];
      bool ok = rsv > 0.f;
      float4 o0, o1;
      float h;
      h = acc[r][0]; o0.x = ok ? (h > 0.f ? h : expm1f(h)) : 0.f;
      h = acc[r][1]; o0.y = ok ? (h > 0.f ? h : expm1f(h)) : 0.f;
      h = acc[r][2]; o0.z = ok ? (h > 0.f ? h : expm1f(h)) : 0.f;
      h = acc[r][3]; o0.w = ok ? (h > 0.f ? h : expm1f(h)) : 0.f;
      h = acc[r][4]; o1.x = ok ? (h > 0.f ? h : expm1f(h)) : 0.f;
      h = acc[r][5]; o1.y = ok ? (h > 0.f ? h : expm1f(h)) : 0.f;
      h = acc[r][6]; o1.z = ok ? (h > 0.f ? h : expm1f(h)) : 0.f;
      h = acc[r][7]; o1.w = ok ? (h > 0.f ? h : expm1f(h)) : 0.f;
      *(float4*)(out + gi * 128 + tn) = o0;
      *(float4*)(out + gi * 128 + tn + 4) = o1;
    }
  }
}

// =====================================================================================

static inline size_t align_up(size_t x, size_t a) { return (x + a - 1) & ~(a - 1); }

extern "C" void kernel_launch(void* const* d_in, const int* in_sizes, int n_in,
                              void* d_out, int out_size, void* d_ws, size_t ws_size,
                              hipStream_t stream) {
  const float* x1 = (const float*)d_in[0];
  const float* x2 = (const float*)d_in[1];
  const float* ee = (const float*)d_in[2];
  const float* a = (const float*)d_in[3];
  const float* a2 = (const float*)d_in[4];
  const int* esrc = (const int*)d_in[5];
  const int* edst = (const int*)d_in[6];
  float* out = (float*)d_out;

  char* base = (char*)d_ws;
  size_t off = 0;
  auto alloc = [&](size_t bytes) -> char* {
    char* p = base + off;
    off = align_up(off + bytes, 256);
    return p;
  };
  float* c = (float*)alloc(320 * 4);
  float* z2g = (float*)alloc(512 * 4);
  float* aT = (float*)alloc(320 * 128 * 4);
  int* rp1 = (int*)alloc((N1V + 1) * 4);
  int* cur1 = (int*)alloc(N1V * 4);
  int* rp2 = (int*)alloc(512 * 4);
  int* partials = (int*)alloc(64 * 4);
  int* hblk = (int*)alloc((size_t)NB * 512 * 4);
  int* tot2 = (int*)alloc(512 * 4);
  int* eidx1 = (int*)alloc(NEV * 4);
  int* eidx2 = (int*)alloc(NEV * 4);
  float* wbuf = (float*)alloc(NEV * 4);
  float* rs1 = (float*)alloc(N1V * 4);
  float* rs2 = (float*)alloc(512 * 4);
  float* sbuf1 = (float*)alloc((size_t)N1V * 192 * 4);
  float* sbuf2 = (float*)alloc(512 * 192 * 4);
  float* acc2 = (float*)alloc(512 * 196 * 4);
  (void)ws_size; (void)out_size; (void)n_in; (void)in_sizes;

  hipMemsetAsync(cur1, 0, N1V * 4, stream);
  hipMemsetAsync(acc2, 0, 512 * 196 * 4, stream);

  hipLaunchKernelGGL(k_prep, dim3(162), dim3(256), 0, stream, a, a2, c, aT);
  hipLaunchKernelGGL(k_z2, dim3(125), dim3(256), 0, stream, x2, c, z2g);
  hipLaunchKernelGGL(k_hist, dim3(NB), dim3(256), 0, stream, esrc, edst, cur1, hblk);
  hipLaunchKernelGGL(k_colscan, dim3(512), dim3(256), 0, stream, hblk, tot2);

  const int nScanBlocks = (N1V + 2047) / 2048;  // 49
  hipLaunchKernelGGL(k_scanA, dim3(nScanBlocks), dim3(256), 0, stream, cur1, rp1, partials, N1V);
  hipLaunchKernelGGL(k_scanB, dim3(1), dim3(512), 0, stream, partials, nScanBlocks, tot2, rp2);
  hipLaunchKernelGGL(k_scanC, dim3((N1V + 255) / 256), dim3(256), 0, stream, rp1, cur1, partials, N1V, NEV);
  hipLaunchKernelGGL(k_scatter, dim3(NB), dim3(256), 0, stream, esrc, edst, cur1, hblk, rp2, eidx1, eidx2);

  hipLaunchKernelGGL(k_src, dim3(N1V / 4), dim3(256), 0, stream,
                     x1, x2, ee, edst, c, z2g, rp1, eidx1, wbuf, sbuf1, rs1);
  hipLaunchKernelGGL(k_dst_partial, dim3(N2V * 8), dim3(256), 0, stream,
                     x1, ee, esrc, rp2, eidx2, wbuf, acc2);
  hipLaunchKernelGGL(k_dst_final, dim3(N2V), dim3(256), 0, stream, acc2, sbuf2, rs2);

  hipLaunchKernelGGL(k_gemm, dim3((N1V + 127) / 128), dim3(256), 0, stream,
                     x1, sbuf1, aT, rs1, out, N1V, 0);
  hipLaunchKernelGGL(k_gemm, dim3((N2V + 127) / 128), dim3(256), 0, stream,
                     x2, sbuf2, aT, rs2, out + (size_t)N1V * 128, N2V, 1);
}